// Round 7
// baseline (114.300 us; speedup 1.0000x reference)
//
#include <hip/hip_runtime.h>
#include <cstddef>

// InfoNCE loss, B=8192, D=128.
// prep: normalize + bf16 cast + (label, conf-sign) + self-dot (+ accum zero)
// sim:  FULL matrix (no symmetry — flush machinery costs more than the saved
//       FLOPs). Grid 32x16 = 512 blocks (2/CU, one exact dispatch wave).
//       Block = 256 rows x 512 cols. Each wave owns 64 rows (4 row-tiles) ->
//       4x B-register reuse per LDS read. Columns staged 128 at a time via
//       async global_load_lds DMA into a double-buffered XOR-swizzled LDS
//       tile (swizzle via per-lane source-address permute; zero VGPR cost).
//       ONE barrier per stage, ONE flush per block. No global atomics:
//       slot (colChunk, row) written exactly once.
// fin1: per-row 16-slot sum + loss, block-reduce, 2 atomics/block into accum
// fin2: out = sum/cnt

#define DDIM 128
#define TEMP_SCALE 14.4269504088896340736f  // (1/0.1) * log2(e), folded into A-side
#define BIGNEG 5e29f

typedef short s8bf __attribute__((ext_vector_type(8)));   // 8 bf16 (4 VGPRs)
typedef float f32x4 __attribute__((ext_vector_type(4)));

__device__ __forceinline__ unsigned short f2bf(float f) {
    unsigned int u = __float_as_uint(f);
    u += 0x7fffu + ((u >> 16) & 1u);
    return (unsigned short)(u >> 16);
}
__device__ __forceinline__ float bf2f(unsigned short h) {
    return __uint_as_float(((unsigned int)h) << 16);
}

// ---------------- prep: one wave per row ----------------
__global__ __launch_bounds__(256) void prep_kernel(
    const float* __restrict__ emb, const int* __restrict__ labels,
    const float* __restrict__ conf,
    short* __restrict__ Ea,   // bf16(SCALE * e)
    short* __restrict__ Eb,   // bf16(e)
    float2* __restrict__ lh,  // (label +-1, sign(conf))
    float* __restrict__ sd,   // scaled self-dot (bf16-rounded)
    float* __restrict__ accum, int B)
{
    if (blockIdx.x == 0 && threadIdx.x == 0) { accum[0] = 0.0f; accum[1] = 0.0f; }

    int wave = threadIdx.x >> 6;
    int lane = threadIdx.x & 63;
    int row  = blockIdx.x * 4 + wave;
    if (row >= B) return;

    float2 x = ((const float2*)(emb + (size_t)row * DDIM))[lane];
    float ss = x.x * x.x + x.y * x.y;
    #pragma unroll
    for (int m = 32; m; m >>= 1) ss += __shfl_xor(ss, m);
    float inv = 1.0f / fmaxf(sqrtf(ss), 1e-12f);

    float e0 = x.x * inv, e1 = x.y * inv;
    unsigned short ea0 = f2bf(TEMP_SCALE * e0), ea1 = f2bf(TEMP_SCALE * e1);
    unsigned short eb0 = f2bf(e0),              eb1 = f2bf(e1);
    *(ushort2*)(Ea + (size_t)row * DDIM + lane * 2) = make_ushort2(ea0, ea1);
    *(ushort2*)(Eb + (size_t)row * DDIM + lane * 2) = make_ushort2(eb0, eb1);

    float p = bf2f(ea0) * bf2f(eb0) + bf2f(ea1) * bf2f(eb1);
    #pragma unroll
    for (int m = 32; m; m >>= 1) p += __shfl_xor(p, m);

    if (lane == 0) {
        sd[row] = p;
        float l = labels[row] ? 1.0f : -1.0f;
        float c = conf[row];
        float h = (c > 0.0f) ? 1.0f : ((c < 0.0f) ? -1.0f : 0.0f);
        lh[row] = make_float2(l, h);
    }
}

// ---------------- sim ----------------
// Async DMA stage of a 128-col stripe into swizzled LDS. LDS side of
// global_load_lds is wave-uniform-base + lane*16; the XOR swizzle (chunk c
// of row r at c^(r&15)) is realized by permuting the per-lane SOURCE
// address: LDS slot s holds global chunk (s & ~15) | ((s ^ (s>>4)) & 15).
__device__ __forceinline__ void stage_async(
    const short* __restrict__ Eb, const float2* __restrict__ lh, int col0,
    int wave, int lane, int4* tileBuf, float2* lhBuf)
{
    const char* gbase = (const char*)(Eb + (size_t)col0 * DDIM);
    #pragma unroll
    for (int i = 0; i < 8; ++i) {
        int s = (wave * 8 + i) * 64 + lane;
        int srcChunk = (s & ~15) | ((s ^ (s >> 4)) & 15);
        __builtin_amdgcn_global_load_lds(
            (const __attribute__((address_space(1))) void*)(gbase + (size_t)srcChunk * 16),
            (__attribute__((address_space(3))) void*)((char*)tileBuf + (size_t)(wave * 8 + i) * 1024),
            16, 0, 0);
    }
    if (wave == 0) {
        __builtin_amdgcn_global_load_lds(
            (const __attribute__((address_space(1))) void*)((const char*)(lh + (size_t)col0) + lane * 16),
            (__attribute__((address_space(3))) void*)lhBuf,
            16, 0, 0);
    }
}

__global__ __launch_bounds__(256, 2) void sim_kernel(
    const short* __restrict__ Ea, const short* __restrict__ Eb,
    const float2* __restrict__ lh,
    float* __restrict__ tpart, float* __restrict__ ppart, int B)
{
    __shared__ int4  tiles[2][128 * 16];   // 2 x 32 KB, swizzled
    __shared__ float2 lhT[2][128];         // 2 x 1 KB
    __shared__ float rT[256], rP[256];     // per-block flush staging

    int tid  = threadIdx.x;
    int lane = tid & 63;
    int wave = tid >> 6;
    int l16  = lane & 15;
    int quad = lane >> 4;

    int rowBase = blockIdx.x * 256 + wave * 64;   // 4 row-tiles: +0,16,32,48
    int cbase   = blockIdx.y * 512;               // 4 stages of 128 cols
    int slot    = blockIdx.y;

    // ---- A fragments (invariant for whole kernel): A[m=l16][k=quad*8+j] ----
    s8bf a[4][4];
    #pragma unroll
    for (int t = 0; t < 4; ++t)
        #pragma unroll
        for (int kc = 0; kc < 4; ++kc)
            a[t][kc] = *(const s8bf*)(Ea + (size_t)(rowBase + t * 16 + l16) * DDIM + kc * 32 + quad * 8);

    // per-element row conf-signs (C/D layout: col = lane&15, row = quad*4 + reg)
    float hi[4][4];
    #pragma unroll
    for (int t = 0; t < 4; ++t)
        #pragma unroll
        for (int r = 0; r < 4; ++r)
            hi[t][r] = lh[rowBase + t * 16 + quad * 4 + r].y;

    float tot[4][4], tP[4][4];
    #pragma unroll
    for (int t = 0; t < 4; ++t)
        #pragma unroll
        for (int r = 0; r < 4; ++r) { tot[t][r] = 0.0f; tP[t][r] = 0.0f; }

    stage_async(Eb, lh, cbase, wave, lane, tiles[0], lhT[0]);
    __syncthreads();   // vmcnt drain: buf0 ready

    int cur = 0;
    for (int g = 0; g < 4; ++g) {
        if (g < 3)
            stage_async(Eb, lh, cbase + (g + 1) * 128, wave, lane, tiles[cur ^ 1], lhT[cur ^ 1]);

        const int4*   tile16 = tiles[cur];
        const float2* lhTile = lhT[cur];

        #pragma unroll
        for (int ct = 0; ct < 8; ++ct) {
            s8bf b[4];
            #pragma unroll
            for (int kc = 0; kc < 4; ++kc)
                b[kc] = *(const s8bf*)&tile16[(ct * 16 + l16) * 16 + ((kc * 4 + quad) ^ l16)];

            f32x4 acc[4];
            #pragma unroll
            for (int t = 0; t < 4; ++t) acc[t] = (f32x4){0.f, 0.f, 0.f, 0.f};
            #pragma unroll
            for (int kc = 0; kc < 4; ++kc)
                #pragma unroll
                for (int t = 0; t < 4; ++t)
                    acc[t] = __builtin_amdgcn_mfma_f32_16x16x32_bf16(a[t][kc], b[kc], acc[t], 0, 0, 0);

            float2 lhj = lhTile[ct * 16 + l16];
            float bp  = BIGNEG * lhj.y;                 // 5e29 * h_j
            float mPc = fmaf(lhj.x, 0.5f, 0.5f);        // (l_j>0)?1:0
            #pragma unroll
            for (int t = 0; t < 4; ++t)
                #pragma unroll
                for (int r = 0; r < 4; ++r) {
                    // bias = fma(h_i, 5e29*h_j, -5e29) in {0,-5e29,-1e30}
                    float e = __builtin_amdgcn_exp2f(acc[t][r] + fmaf(hi[t][r], bp, -BIGNEG));
                    tot[t][r] += e;
                    tP[t][r]   = fmaf(mPc, e, tP[t][r]);
                }
        }

        __syncthreads();   // drains next stage's DMA; all waves done with cur
        cur ^= 1;
    }

    // ---- single flush: butterfly over 16 col-lanes -> LDS -> coalesced ----
    #pragma unroll
    for (int t = 0; t < 4; ++t)
        #pragma unroll
        for (int r = 0; r < 4; ++r) {
            float tt = tot[t][r], pp = tP[t][r];
            #pragma unroll
            for (int m = 1; m < 16; m <<= 1) {
                tt += __shfl_xor(tt, m);
                pp += __shfl_xor(pp, m);
            }
            if (l16 == 0) {
                int o = wave * 64 + t * 16 + quad * 4 + r;
                float li = lh[blockIdx.x * 256 + o].x;
                rT[o] = tt;
                rP[o] = (li > 0.0f) ? pp : (tt - pp);   // pos incl. diagonal
            }
        }
    __syncthreads();

    int grow = blockIdx.x * 256 + tid;
    tpart[(size_t)slot * B + grow] = rT[tid];
    ppart[(size_t)slot * B + grow] = rP[tid];
}

// ---------------- fin1: 16-slot sum + per-row loss + block reduce ----------------
__global__ __launch_bounds__(256) void fin1_kernel(
    const float* __restrict__ tpart, const float* __restrict__ ppart,
    const float* __restrict__ sd, const float2* __restrict__ lh,
    float* __restrict__ accum, int B)
{
    __shared__ float ssum[4], scnt[4];
    int i = blockIdx.x * 256 + threadIdx.x;

    float tot = 0.0f, pos = 0.0f;
    #pragma unroll
    for (int s = 0; s < 16; ++s) {
        tot += tpart[(size_t)s * B + i];
        pos += ppart[(size_t)s * B + i];
    }
    float diag = (lh[i].y != 0.0f) ? __builtin_amdgcn_exp2f(sd[i]) : 0.0f;
    float p   = pos - diag;
    float neg = tot - pos;     // diag cancels (in both tot and pos)
    float sum = 0.0f, cnt = 0.0f;
    if (p > 0.0f && neg > 0.0f) {
        sum = 0.69314718055994530942f *
              (__builtin_amdgcn_logf(p + neg + 1e-8f) - __builtin_amdgcn_logf(p));
        cnt = 1.0f;
    }
    #pragma unroll
    for (int m = 32; m; m >>= 1) {
        sum += __shfl_xor(sum, m);
        cnt += __shfl_xor(cnt, m);
    }
    int wave = threadIdx.x >> 6, lane = threadIdx.x & 63;
    if (lane == 0) { ssum[wave] = sum; scnt[wave] = cnt; }
    __syncthreads();
    if (threadIdx.x == 0) {
        atomicAdd(&accum[0], ssum[0] + ssum[1] + ssum[2] + ssum[3]);
        atomicAdd(&accum[1], scnt[0] + scnt[1] + scnt[2] + scnt[3]);
    }
}

__global__ void fin2_kernel(const float* __restrict__ accum, float* __restrict__ out) {
    float S = accum[0], C = accum[1];
    out[0] = (C > 0.0f) ? S / fmaxf(C, 1.0f) : 0.0f;
}

extern "C" void kernel_launch(void* const* d_in, const int* in_sizes, int n_in,
                              void* d_out, int out_size, void* d_ws, size_t ws_size,
                              hipStream_t stream) {
    const float* emb    = (const float*)d_in[0];
    const int*   labels = (const int*)d_in[1];
    const float* conf   = (const float*)d_in[2];
    float* out = (float*)d_out;
    int B = in_sizes[1];   // 8192

    char* ws = (char*)d_ws;
    size_t off = 0;
    short*  Ea    = (short*)(ws + off);  off += (size_t)B * DDIM * 2;
    short*  Eb    = (short*)(ws + off);  off += (size_t)B * DDIM * 2;
    float2* lhp   = (float2*)(ws + off); off += (size_t)B * 8;
    float*  sd    = (float*)(ws + off);  off += (size_t)B * 4;
    float*  tpart = (float*)(ws + off);  off += (size_t)16 * B * 4;
    float*  ppart = (float*)(ws + off);  off += (size_t)16 * B * 4;
    float*  accum = (float*)(ws + off);  off += 64;

    prep_kernel<<<B / 4, 256, 0, stream>>>(emb, labels, conf, Ea, Eb, lhp, sd, accum, B);

    // 32 row-blocks x 16 col-chunks = 512 blocks = one exact wave (2/CU, 70KB LDS)
    sim_kernel<<<dim3(B / 256, 16), 256, 0, stream>>>(Ea, Eb, lhp, tpart, ppart, B);

    fin1_kernel<<<B / 256, 256, 0, stream>>>(tpart, ppart, sd, lhp, accum, B);
    fin2_kernel<<<1, 1, 0, stream>>>(accum, out);
}